// Round 5
// baseline (3260.411 us; speedup 1.0000x reference)
//
#include <hip/hip_runtime.h>
#include <stdint.h>

#define NN 8192
#define DD 64

// =====================================================================
// K1: k_pre — 64-row tile: transpose x -> xT (if ws allows) + squared norms.
// sq chain MUST match the k_cand dot chain so that d_ii == 0 exactly.
// =====================================================================
__global__ __launch_bounds__(256) void k_pre(const float* __restrict__ x, float* __restrict__ xT,
                                             float* __restrict__ sq, int do_tr){
  __shared__ float tile[64*65];
  const int tid = threadIdx.x;
  const int b = blockIdx.x;
  for (int k = 0; k < 4; ++k){
    const int idx4 = tid + k*256;
    const float4 v = ((const float4*)(x + (size_t)b*4096))[idx4];
    const int row = idx4 >> 4, d0 = (idx4 & 15) * 4;
    tile[row*65 + d0 + 0] = v.x;
    tile[row*65 + d0 + 1] = v.y;
    tile[row*65 + d0 + 2] = v.z;
    tile[row*65 + d0 + 3] = v.w;
  }
  __syncthreads();
  if (do_tr){
    const int jj = tid & 15;
    const int dq = tid >> 4;
    for (int k = 0; k < 4; ++k){
      const int d = dq + 16*k;
      float4 o;
      o.x = tile[(jj*4+0)*65 + d];
      o.y = tile[(jj*4+1)*65 + d];
      o.z = tile[(jj*4+2)*65 + d];
      o.w = tile[(jj*4+3)*65 + d];
      ((float4*)xT)[(size_t)d*2048 + b*16 + jj] = o;
    }
  }
  if (tid < 64){
    float acc = 0.f;
    const float* rp = tile + tid*65;
    for (int d = 0; d < 64; ++d) acc = fmaf(rp[d], rp[d], acc);
    sq[b*64 + tid] = acc;
  }
}

// =====================================================================
// K2: k_cand — unchanged from round 4 (bit-exact kNN/KDE path).
// =====================================================================
template<bool XT>
__device__ __forceinline__ void dists_1024(const float* __restrict__ x, const float* __restrict__ xT,
                                           const float* __restrict__ xi, int jbase, int tid,
                                           float acc[8][4]){
#pragma unroll
  for (int r = 0; r < 8; ++r)
#pragma unroll
    for (int q = 0; q < 4; ++q) acc[r][q] = 0.f;
  const int j0 = jbase + tid*4;
  for (int dq = 0; dq < 16; ++dq){
    float4 vj[4];
    if (XT){
#pragma unroll
      for (int s = 0; s < 4; ++s)
        vj[s] = ((const float4*)xT)[(size_t)(dq*4+s)*2048 + (j0 >> 2)];
    } else {
#pragma unroll
      for (int s = 0; s < 4; ++s){
        const int d = dq*4 + s;
        vj[s].x = x[(size_t)(j0+0)*64 + d];
        vj[s].y = x[(size_t)(j0+1)*64 + d];
        vj[s].z = x[(size_t)(j0+2)*64 + d];
        vj[s].w = x[(size_t)(j0+3)*64 + d];
      }
    }
#pragma unroll
    for (int r = 0; r < 8; ++r){
      const float4 wv = ((const float4*)(xi + r*64))[dq];
      acc[r][0] = fmaf(vj[0].x, wv.x, acc[r][0]);
      acc[r][1] = fmaf(vj[0].y, wv.x, acc[r][1]);
      acc[r][2] = fmaf(vj[0].z, wv.x, acc[r][2]);
      acc[r][3] = fmaf(vj[0].w, wv.x, acc[r][3]);
      acc[r][0] = fmaf(vj[1].x, wv.y, acc[r][0]);
      acc[r][1] = fmaf(vj[1].y, wv.y, acc[r][1]);
      acc[r][2] = fmaf(vj[1].z, wv.y, acc[r][2]);
      acc[r][3] = fmaf(vj[1].w, wv.y, acc[r][3]);
      acc[r][0] = fmaf(vj[2].x, wv.z, acc[r][0]);
      acc[r][1] = fmaf(vj[2].y, wv.z, acc[r][1]);
      acc[r][2] = fmaf(vj[2].z, wv.z, acc[r][2]);
      acc[r][3] = fmaf(vj[2].w, wv.z, acc[r][3]);
      acc[r][0] = fmaf(vj[3].x, wv.w, acc[r][0]);
      acc[r][1] = fmaf(vj[3].y, wv.w, acc[r][1]);
      acc[r][2] = fmaf(vj[3].z, wv.w, acc[r][2]);
      acc[r][3] = fmaf(vj[3].w, wv.w, acc[r][3]);
    }
  }
}

template<bool XT>
__global__ __launch_bounds__(256) void k_cand(const float* __restrict__ x, const float* __restrict__ xT,
                                              const float* __restrict__ sq,
                                              float* __restrict__ res, unsigned short* __restrict__ nn16){
  __shared__ float xi[8*64];
  __shared__ float sqi_s[8];
  __shared__ float tubs[8];
  __shared__ __align__(16) unsigned long long cand[8*512];
  __shared__ unsigned ccnt[8];
  float* samp = (float*)cand;
  const int tid = threadIdx.x;
  const int i0 = blockIdx.x * 8;
  for (int t = tid; t < 8*64; t += 256) xi[t] = x[(size_t)i0*64 + t];
  if (tid < 8){ sqi_s[tid] = sq[i0+tid]; ccnt[tid] = 0u; }
  __syncthreads();
  float sqir[8];
#pragma unroll
  for (int r = 0; r < 8; ++r) sqir[r] = sqi_s[r];

  const int w0 = (blockIdx.x * 1024) & 8191;
  {
    float acc[8][4];
    dists_1024<XT>(x, xT, xi, w0, tid, acc);
    float sqj[4];
#pragma unroll
    for (int q = 0; q < 4; ++q) sqj[q] = sq[w0 + tid*4 + q];
#pragma unroll
    for (int r = 0; r < 8; ++r)
#pragma unroll
      for (int q = 0; q < 4; ++q)
        samp[r*1024 + tid*4 + q] = (sqir[r] + sqj[q]) - 2.f*acc[r][q];
  }
  __syncthreads();
  {
    const int wv = tid >> 6, lane = tid & 63;
    for (int rr = 0; rr < 2; ++rr){
      const int r = wv + rr*4;
      float v[16];
#pragma unroll
      for (int k2 = 0; k2 < 16; ++k2) v[k2] = samp[r*1024 + lane + 64*k2];
      unsigned lo = 0u, hi = 0x7F800001u;
      while (hi - lo > 1u){
        const unsigned mid = (lo + hi) >> 1;
        const float pf = __uint_as_float(mid);
        int c = 0;
#pragma unroll
        for (int k2 = 0; k2 < 16; ++k2) c += (v[k2] < pf) ? 1 : 0;
#pragma unroll
        for (int off = 32; off; off >>= 1) c += __shfl_xor(c, off);
        if (c >= 32) hi = mid; else lo = mid;
      }
      if (lane == 0) tubs[r] = __uint_as_float(hi);
    }
  }
  __syncthreads();
  float tubr[8];
#pragma unroll
  for (int r = 0; r < 8; ++r) tubr[r] = tubs[r];
  for (int t = tid; t < 8*512; t += 256) cand[t] = ~0ULL;
  __syncthreads();

  for (int pass = 0; pass < 8; ++pass){
    const int jb = pass*1024;
    float acc[8][4];
    dists_1024<XT>(x, xT, xi, jb, tid, acc);
    const int j0 = jb + tid*4;
    float sqj[4];
#pragma unroll
    for (int q = 0; q < 4; ++q) sqj[q] = sq[j0 + q];
#pragma unroll
    for (int r = 0; r < 8; ++r){
#pragma unroll
      for (int q = 0; q < 4; ++q){
        const float dist = (sqir[r] + sqj[q]) - 2.f*acc[r][q];
        if (dist < tubr[r]){
          const unsigned pos = atomicAdd(&ccnt[r], 1u);
          if (pos < 512u){
            unsigned u = __float_as_uint(dist);
            u = ((int)u < 0) ? ~u : (u | 0x80000000u);
            cand[r*512 + pos] = (((unsigned long long)u) << 13) | (unsigned)(j0 + q);
          }
        }
      }
    }
  }
  __syncthreads();

  for (int k = 2; k <= 512; k <<= 1){
    for (int jj2 = k >> 1; jj2 > 0; jj2 >>= 1){
      const int mm = tid;
      const int i = ((mm & ~(jj2-1)) << 1) | (mm & (jj2-1));
      const int p = i | jj2;
      const bool up2 = ((i & k) == 0);
#pragma unroll
      for (int r = 0; r < 8; ++r){
        unsigned long long a = cand[r*512+i], bb = cand[r*512+p];
        if ((a > bb) == up2){ cand[r*512+i] = bb; cand[r*512+p] = a; }
      }
      __syncthreads();
    }
  }

  const int wv2 = tid >> 6, lane2 = tid & 63;
  for (int rr = 0; rr < 2; ++rr){
    const int r = wv2*2 + rr;
    const unsigned long long kk = cand[r*512 + lane2];
    float e = 0.f;
    if (lane2 < 50){
      unsigned u2 = (unsigned)(kk >> 13);
      u2 = (u2 & 0x80000000u) ? (u2 & 0x7FFFFFFFu) : ~u2;
      e = expf(-__uint_as_float(u2) / 30.f);
    }
#pragma unroll
    for (int off = 32; off; off >>= 1) e += __shfl_down(e, off);
    if (lane2 == 0) res[i0+r] = e / 1500.f;
    if (lane2 < 16) nn16[(size_t)(i0+r)*16 + lane2] = (unsigned short)(kk & 8191ULL);
  }
}

// =====================================================================
// K3: k_suf — fused sort + union-find (peak-collapsed, event-compacted)
// + loss. Single block, 1024 threads.
//
// Peak collapse: with THRESHOLD=1.0 every emitted pair merges, so at step
// p find(u) == find(P(u)) where P(u) = root of the static u_max forest
// (each point -> its max upward neighbour). P computed via parallel
// pointer jumping. A point whose valid ups all share the same raw P makes
// NO state change, so only "event" points (>=2 distinct raw P) are
// processed sequentially. Events detected + compacted in parallel.
// =====================================================================
__global__ __launch_bounds__(1024) void k_suf(const float* __restrict__ res,
                                              const unsigned short* __restrict__ nn16,
                                              unsigned short* __restrict__ ups_t,
                                              unsigned short* __restrict__ evtbuf,
                                              float* __restrict__ out){
  __shared__ __align__(16) unsigned long long keys[NN]; // 64KB, repurposed later
  __shared__ __align__(16) unsigned short rankv[NN];    // 16KB, -> peakpar
  __shared__ __align__(16) unsigned short death[NN];    // 16KB
  __shared__ float red[1024];                            // 4KB (max, then sred)
  __shared__ unsigned fl[64];
  __shared__ unsigned idxs[64];
  __shared__ unsigned ecnt_s;
  __shared__ unsigned long long sel[10];
  // keys region repurposed after the sort (register-staged to avoid aliasing):
  float*          dens    = (float*)keys;                              // [0,32KB)
  unsigned short* P       = (unsigned short*)keys + 16384;             // [32KB,48KB)
  unsigned short* evtp    = (unsigned short*)keys + 24576;             // [48KB,64KB)
  unsigned long long* kred = (unsigned long long*)((char*)keys + 49152); // aliases evtp (dead at loss)

  const int tid  = threadIdx.x;
  const int lane = tid & 63;

  // ---- A0: max(res) ----
  float m = 0.f;
  for (int t = tid; t < NN; t += 1024) m = fmaxf(m, res[t]);
  red[tid] = m; __syncthreads();
  for (int o = 512; o; o >>= 1){ if (tid < o) red[tid] = fmaxf(red[tid], red[tid+o]); __syncthreads(); }
  const float mr = red[0];

  // ---- A1: keys + bitonic sort (bit-exact vs rounds 2-4) ----
  for (int t = tid; t < NN; t += 1024){
    const float dnv = res[t] / mr;
    keys[t] = (((unsigned long long)__float_as_uint(dnv)) << 13) | (unsigned)t;
  }
  __syncthreads();
  for (int k = 2; k <= NN; k <<= 1){
    for (int j = k >> 1; j > 0; j >>= 1){
      for (int m2 = tid; m2 < NN/2; m2 += 1024){
        const int i = ((m2 & ~(j-1)) << 1) | (m2 & (j-1));
        const int p = i | j;
        const bool up = ((i & k) == 0);
        unsigned long long a = keys[i], b = keys[p];
        if ((a > b) == up){ keys[i] = b; keys[p] = a; }
      }
      __syncthreads();
    }
  }
  // ---- A2: rank inverse ----
  for (int t = tid; t < NN; t += 1024)
    rankv[(unsigned)(keys[t] & 8191ULL)] = (unsigned short)t;
  __syncthreads();

  // ---- A3: ups lists (desc, grouped-transposed) + stage dens/umax in regs ----
  float dreg[8];
  unsigned short o0reg[8];
  for (int pp = 0; pp < 8; ++pp){
    const int p = tid + pp*1024;
    const unsigned long long kk = keys[p];
    dreg[pp] = __uint_as_float((unsigned)(kk >> 13));
    const unsigned orig = (unsigned)(kk & 8191ULL);
    unsigned short outv[16];
    int cnt = 0;
    for (int k = 0; k < 16; ++k){
      const unsigned r = rankv[nn16[(size_t)orig*16 + k]];
      if ((int)r > p){
        int q = cnt++;
        while (q > 0 && outv[q-1] < (unsigned short)r){ outv[q] = outv[q-1]; --q; }
        outv[q] = (unsigned short)r;
      }
    }
    for (int k = cnt; k < 16; ++k) outv[k] = 0;
    o0reg[pp] = outv[0];
    unsigned short* dst = ups_t + (size_t)(p >> 2)*64 + (3 - (p & 3))*16;
    uint4 a, b;
    a.x = (unsigned)outv[0] | ((unsigned)outv[1] << 16);
    a.y = (unsigned)outv[2] | ((unsigned)outv[3] << 16);
    a.z = (unsigned)outv[4] | ((unsigned)outv[5] << 16);
    a.w = (unsigned)outv[6] | ((unsigned)outv[7] << 16);
    b.x = (unsigned)outv[8] | ((unsigned)outv[9] << 16);
    b.y = (unsigned)outv[10] | ((unsigned)outv[11] << 16);
    b.z = (unsigned)outv[12] | ((unsigned)outv[13] << 16);
    b.w = (unsigned)outv[14] | ((unsigned)outv[15] << 16);
    ((uint4*)dst)[0] = a;
    ((uint4*)dst)[1] = b;
  }
  __syncthreads();   // all keys/rankv reads done; safe to repurpose

  // ---- A4: write dens/P, init peakpar/death ----
  unsigned short* peakpar = rankv;
  for (int pp = 0; pp < 8; ++pp){
    const int p = tid + pp*1024;
    dens[p] = dreg[pp];
    P[p] = (o0reg[pp] == 0) ? (unsigned short)p : o0reg[pp];
    peakpar[p] = (unsigned short)p;
    death[p] = 0xFFFFu;
  }
  if (tid == 0) ecnt_s = 0u;
  __syncthreads();

  // ---- A5: pointer jumping (u_max forest roots). Races across waves are
  // benign: any interleaving writes an ancestor; 13 rounds cover depth 8192.
  for (int rd = 0; rd < 13; ++rd){
    for (int pp = 0; pp < 8; ++pp){
      const int p = tid + pp*1024;
      const unsigned v = P[p];
      const unsigned w2 = P[v];
      if (w2 != v) P[p] = (unsigned short)w2;
    }
    __syncthreads();
  }

  // ---- A6: event detection + ordered compaction (desc p) ----
  const int sg = tid >> 4, slot = tid & 15;
  for (int c = 0; c < 128; ++c){
    const int p = 8191 - (c*64 + sg);
    const unsigned u = ups_t[(size_t)(p >> 2)*64 + (3 - (p & 3))*16 + slot];
    const unsigned mapped = (u != 0u) ? (unsigned)P[u] : 0xFFFFu;
    const unsigned m0 = (unsigned)__shfl((int)mapped, (lane & ~15));
    const unsigned u0 = (unsigned)__shfl((int)u, (lane & ~15));
    const bool ne = (u != 0u) && (mapped != m0);
    const unsigned long long wm = __ballot(ne);
    const bool isevt = (u0 != 0u) && (((wm >> (lane & 48)) & 0xFFFFULL) != 0ULL);
    if (slot == 0) fl[sg] = isevt ? 1u : 0u;
    __syncthreads();
    if (tid < 64){
      const unsigned f = fl[tid];
      const unsigned long long em = __ballot(f != 0u);
      const unsigned base = ecnt_s;
      idxs[tid] = base + (unsigned)__popcll(em & ((1ULL << tid) - 1ULL));
      if (tid == 0) ecnt_s = base + (unsigned)__popcll(em);
    }
    __syncthreads();
    if (isevt){
      const unsigned myidx = idxs[sg];
      evtbuf[(size_t)myidx*16 + slot] = (unsigned short)mapped;
      if (slot == 0) evtp[myidx] = (unsigned short)p;
    }
  }
  __syncthreads();

  // ---- A7: sequential event loop (wave 0 only) ----
  const unsigned ec = ecnt_s;
  if (tid < 64 && ec > 0){
    int c0 = (int)evtbuf[lane];          // batch 0 (events 0..3)
    int c1 = (int)evtbuf[64 + lane];     // batch 1
    int pk_cur = __shfl(c0, lane & 15);
    int pr_cur = (int)peakpar[pk_cur & 8191];
    for (unsigned ev = 0; ev < ec; ++ev){
      const int q = (int)(ev & 3u);
      if (q == 0 && ev > 0){
        c0 = c1;
        const size_t a = ((size_t)((ev >> 2) + 1u))*64 + (size_t)lane;
        c1 = (int)evtbuf[(a < (size_t)NN*16) ? a : ((size_t)NN*16 - 1)];
      }
      const unsigned evn = ev + 1u;
      const int qn = (int)(evn & 3u);
      int pkn = __shfl((qn != 0) ? c0 : c1, (qn << 4) | (lane & 15));
      if (evn >= ec) pkn = 0xFFFF;
      int prn = (int)peakpar[pkn & 8191];        // hop-1 prefetch (fixed on deaths below)
      const int p_v = (int)evtp[ev];             // LDS broadcast
      const bool val = (lane < 16) && (pk_cur != 0xFFFF);
      int r  = val ? pk_cur : 0;
      int pr = val ? pr_cur : 0;
      while (__ballot(val && (pr != r))){
        const bool go = val && (pr != r);
        const int g2 = go ? (int)peakpar[pr] : 0;
        if (go){ peakpar[r] = (unsigned short)g2; r = pr; pr = g2; }  // path halving
      }
      const int r_sur = __builtin_amdgcn_readlane(r, 0);  // slot0 = P(u_max) side
      unsigned long long dm = __ballot(val && (r != r_sur));
      while (dm){
        const int b = (int)__ffsll(dm) - 1;
        const int d = __builtin_amdgcn_readlane(r, b);
        if (lane == b){ death[d] = (unsigned short)p_v; peakpar[d] = (unsigned short)r_sur; }
        prn = (prn == d) ? r_sur : prn;          // keep prefetch live
        dm &= ~__ballot(val && (r == d));
        r = (r == d) ? r_sur : r;
      }
      pk_cur = pkn; pr_cur = prn;
    }
  }
  __syncthreads();

  // ---- A8: loss (round-2 k_loss structure, bit-exact) ----
  float s = 0.f;
  for (int e = tid; e < NN; e += 1024){
    const int dr = death[e];
    if (dr != 0xFFFF) s += dens[e] - dens[dr];
  }
  red[tid] = s; __syncthreads();
  for (int o = 512; o; o >>= 1){ if (tid < o) red[tid] += red[tid+o]; __syncthreads(); }
  const float S = red[0];
  unsigned long long last = ~0ULL;
  for (int t10 = 0; t10 < 10; ++t10){
    unsigned long long km = 0ULL;
    for (int e = tid; e < NN; e += 1024){
      const int dr = death[e];
      if (dr != 0xFFFF){
        const float pers = dens[e] - dens[dr];
        const unsigned long long k = (((unsigned long long)__float_as_uint(pers)) << 13) | (unsigned)e;
        if (k < last && k > km) km = k;
      }
    }
    kred[tid] = km; __syncthreads();
    for (int o = 512; o; o >>= 1){ if (tid < o) kred[tid] = (kred[tid] > kred[tid+o]) ? kred[tid] : kred[tid+o]; __syncthreads(); }
    const unsigned long long st = kred[0];
    if (tid == 0) sel[t10] = st;
    last = st;
    __syncthreads();
  }
  if (tid == 0){
    float top = 0.f;
    for (int t10 = 0; t10 < 10; ++t10)
      if (sel[t10]) top += __uint_as_float((unsigned)(sel[t10] >> 13));
    float strong = 0.f, dest0 = 0.f, dest1 = 0.f;
    if (sel[0]){
      const unsigned e0 = (unsigned)(sel[0] & 8191ULL);
      dest0 = dens[e0]; dest1 = dens[death[e0]];
    }
    for (int t10 = 1; t10 < 10; ++t10){
      if (!sel[t10]) continue;
      const unsigned e = (unsigned)(sel[t10] & 8191ULL);
      const float a = dens[e] - dest0;
      const float b = dens[death[e]] - dest1;
      strong += sqrtf(a*a + b*b);
    }
    out[0] = (S - top) / 1.41421356237309515f + strong;
  }
}

// =====================================================================
// launch — 3 dispatches
// =====================================================================
extern "C" void kernel_launch(void* const* d_in, const int* in_sizes, int n_in,
                              void* d_out, int out_size, void* d_ws, size_t ws_size,
                              hipStream_t stream){
  const float* x = (const float*)d_in[0];
  char* w = (char*)d_ws;
  float*          sq     = (float*)(w + 0);                 // 32KB
  float*          res    = (float*)(w + 32768);             // 32KB
  unsigned short* nn16   = (unsigned short*)(w + 65536);    // 256KB (dead after A3)
  unsigned short* evtbuf = (unsigned short*)(w + 65536);    // aliases nn16 (written in A6)
  unsigned short* ups_t  = (unsigned short*)(w + 327680);   // 256KB
  float*          xT     = (float*)(w + 589824);            // 2MB (optional)
  const int use_xt = (ws_size >= (size_t)(589824 + NN*DD*4)) ? 1 : 0;

  k_pre<<<128, 256, 0, stream>>>(x, xT, sq, use_xt);
  if (use_xt) k_cand<true ><<<1024, 256, 0, stream>>>(x, xT, sq, res, nn16);
  else        k_cand<false><<<1024, 256, 0, stream>>>(x, xT, sq, res, nn16);
  k_suf<<<1, 1024, 0, stream>>>(res, nn16, ups_t, evtbuf, (float*)d_out);
}

// Round 6
// 1060.970 us; speedup vs baseline: 3.0730x; 3.0730x over previous
//
#include <hip/hip_runtime.h>
#include <stdint.h>

#define NN 8192
#define DD 64

// =====================================================================
// K1: k_pre — 64-row tile: transpose x -> xT (if ws allows) + squared norms.
// sq chain MUST match the k_cand dot chain so that d_ii == 0 exactly.
// =====================================================================
__global__ __launch_bounds__(256) void k_pre(const float* __restrict__ x, float* __restrict__ xT,
                                             float* __restrict__ sq, int do_tr){
  __shared__ float tile[64*65];
  const int tid = threadIdx.x;
  const int b = blockIdx.x;
  for (int k = 0; k < 4; ++k){
    const int idx4 = tid + k*256;
    const float4 v = ((const float4*)(x + (size_t)b*4096))[idx4];
    const int row = idx4 >> 4, d0 = (idx4 & 15) * 4;
    tile[row*65 + d0 + 0] = v.x;
    tile[row*65 + d0 + 1] = v.y;
    tile[row*65 + d0 + 2] = v.z;
    tile[row*65 + d0 + 3] = v.w;
  }
  __syncthreads();
  if (do_tr){
    const int jj = tid & 15;
    const int dq = tid >> 4;
    for (int k = 0; k < 4; ++k){
      const int d = dq + 16*k;
      float4 o;
      o.x = tile[(jj*4+0)*65 + d];
      o.y = tile[(jj*4+1)*65 + d];
      o.z = tile[(jj*4+2)*65 + d];
      o.w = tile[(jj*4+3)*65 + d];
      ((float4*)xT)[(size_t)d*2048 + b*16 + jj] = o;
    }
  }
  if (tid < 64){
    float acc = 0.f;
    const float* rp = tile + tid*65;
    for (int d = 0; d < 64; ++d) acc = fmaf(rp[d], rp[d], acc);
    sq[b*64 + tid] = acc;
  }
}

// =====================================================================
// K2: k_cand — unchanged (bit-exact kNN/KDE path).
// =====================================================================
template<bool XT>
__device__ __forceinline__ void dists_1024(const float* __restrict__ x, const float* __restrict__ xT,
                                           const float* __restrict__ xi, int jbase, int tid,
                                           float acc[8][4]){
#pragma unroll
  for (int r = 0; r < 8; ++r)
#pragma unroll
    for (int q = 0; q < 4; ++q) acc[r][q] = 0.f;
  const int j0 = jbase + tid*4;
  for (int dq = 0; dq < 16; ++dq){
    float4 vj[4];
    if (XT){
#pragma unroll
      for (int s = 0; s < 4; ++s)
        vj[s] = ((const float4*)xT)[(size_t)(dq*4+s)*2048 + (j0 >> 2)];
    } else {
#pragma unroll
      for (int s = 0; s < 4; ++s){
        const int d = dq*4 + s;
        vj[s].x = x[(size_t)(j0+0)*64 + d];
        vj[s].y = x[(size_t)(j0+1)*64 + d];
        vj[s].z = x[(size_t)(j0+2)*64 + d];
        vj[s].w = x[(size_t)(j0+3)*64 + d];
      }
    }
#pragma unroll
    for (int r = 0; r < 8; ++r){
      const float4 wv = ((const float4*)(xi + r*64))[dq];
      acc[r][0] = fmaf(vj[0].x, wv.x, acc[r][0]);
      acc[r][1] = fmaf(vj[0].y, wv.x, acc[r][1]);
      acc[r][2] = fmaf(vj[0].z, wv.x, acc[r][2]);
      acc[r][3] = fmaf(vj[0].w, wv.x, acc[r][3]);
      acc[r][0] = fmaf(vj[1].x, wv.y, acc[r][0]);
      acc[r][1] = fmaf(vj[1].y, wv.y, acc[r][1]);
      acc[r][2] = fmaf(vj[1].z, wv.y, acc[r][2]);
      acc[r][3] = fmaf(vj[1].w, wv.y, acc[r][3]);
      acc[r][0] = fmaf(vj[2].x, wv.z, acc[r][0]);
      acc[r][1] = fmaf(vj[2].y, wv.z, acc[r][1]);
      acc[r][2] = fmaf(vj[2].z, wv.z, acc[r][2]);
      acc[r][3] = fmaf(vj[2].w, wv.z, acc[r][3]);
      acc[r][0] = fmaf(vj[3].x, wv.w, acc[r][0]);
      acc[r][1] = fmaf(vj[3].y, wv.w, acc[r][1]);
      acc[r][2] = fmaf(vj[3].z, wv.w, acc[r][2]);
      acc[r][3] = fmaf(vj[3].w, wv.w, acc[r][3]);
    }
  }
}

template<bool XT>
__global__ __launch_bounds__(256) void k_cand(const float* __restrict__ x, const float* __restrict__ xT,
                                              const float* __restrict__ sq,
                                              float* __restrict__ res, unsigned short* __restrict__ nn16){
  __shared__ float xi[8*64];
  __shared__ float sqi_s[8];
  __shared__ float tubs[8];
  __shared__ __align__(16) unsigned long long cand[8*512];
  __shared__ unsigned ccnt[8];
  float* samp = (float*)cand;
  const int tid = threadIdx.x;
  const int i0 = blockIdx.x * 8;
  for (int t = tid; t < 8*64; t += 256) xi[t] = x[(size_t)i0*64 + t];
  if (tid < 8){ sqi_s[tid] = sq[i0+tid]; ccnt[tid] = 0u; }
  __syncthreads();
  float sqir[8];
#pragma unroll
  for (int r = 0; r < 8; ++r) sqir[r] = sqi_s[r];

  const int w0 = (blockIdx.x * 1024) & 8191;
  {
    float acc[8][4];
    dists_1024<XT>(x, xT, xi, w0, tid, acc);
    float sqj[4];
#pragma unroll
    for (int q = 0; q < 4; ++q) sqj[q] = sq[w0 + tid*4 + q];
#pragma unroll
    for (int r = 0; r < 8; ++r)
#pragma unroll
      for (int q = 0; q < 4; ++q)
        samp[r*1024 + tid*4 + q] = (sqir[r] + sqj[q]) - 2.f*acc[r][q];
  }
  __syncthreads();
  {
    const int wv = tid >> 6, lane = tid & 63;
    for (int rr = 0; rr < 2; ++rr){
      const int r = wv + rr*4;
      float v[16];
#pragma unroll
      for (int k2 = 0; k2 < 16; ++k2) v[k2] = samp[r*1024 + lane + 64*k2];
      unsigned lo = 0u, hi = 0x7F800001u;
      while (hi - lo > 1u){
        const unsigned mid = (lo + hi) >> 1;
        const float pf = __uint_as_float(mid);
        int c = 0;
#pragma unroll
        for (int k2 = 0; k2 < 16; ++k2) c += (v[k2] < pf) ? 1 : 0;
#pragma unroll
        for (int off = 32; off; off >>= 1) c += __shfl_xor(c, off);
        if (c >= 32) hi = mid; else lo = mid;
      }
      if (lane == 0) tubs[r] = __uint_as_float(hi);
    }
  }
  __syncthreads();
  float tubr[8];
#pragma unroll
  for (int r = 0; r < 8; ++r) tubr[r] = tubs[r];
  for (int t = tid; t < 8*512; t += 256) cand[t] = ~0ULL;
  __syncthreads();

  for (int pass = 0; pass < 8; ++pass){
    const int jb = pass*1024;
    float acc[8][4];
    dists_1024<XT>(x, xT, xi, jb, tid, acc);
    const int j0 = jb + tid*4;
    float sqj[4];
#pragma unroll
    for (int q = 0; q < 4; ++q) sqj[q] = sq[j0 + q];
#pragma unroll
    for (int r = 0; r < 8; ++r){
#pragma unroll
      for (int q = 0; q < 4; ++q){
        const float dist = (sqir[r] + sqj[q]) - 2.f*acc[r][q];
        if (dist < tubr[r]){
          const unsigned pos = atomicAdd(&ccnt[r], 1u);
          if (pos < 512u){
            unsigned u = __float_as_uint(dist);
            u = ((int)u < 0) ? ~u : (u | 0x80000000u);
            cand[r*512 + pos] = (((unsigned long long)u) << 13) | (unsigned)(j0 + q);
          }
        }
      }
    }
  }
  __syncthreads();

  for (int k = 2; k <= 512; k <<= 1){
    for (int jj2 = k >> 1; jj2 > 0; jj2 >>= 1){
      const int mm = tid;
      const int i = ((mm & ~(jj2-1)) << 1) | (mm & (jj2-1));
      const int p = i | jj2;
      const bool up2 = ((i & k) == 0);
#pragma unroll
      for (int r = 0; r < 8; ++r){
        unsigned long long a = cand[r*512+i], bb = cand[r*512+p];
        if ((a > bb) == up2){ cand[r*512+i] = bb; cand[r*512+p] = a; }
      }
      __syncthreads();
    }
  }

  const int wv2 = tid >> 6, lane2 = tid & 63;
  for (int rr = 0; rr < 2; ++rr){
    const int r = wv2*2 + rr;
    const unsigned long long kk = cand[r*512 + lane2];
    float e = 0.f;
    if (lane2 < 50){
      unsigned u2 = (unsigned)(kk >> 13);
      u2 = (u2 & 0x80000000u) ? (u2 & 0x7FFFFFFFu) : ~u2;
      e = expf(-__uint_as_float(u2) / 30.f);
    }
#pragma unroll
    for (int off = 32; off; off >>= 1) e += __shfl_down(e, off);
    if (lane2 == 0) res[i0+r] = e / 1500.f;
    if (lane2 < 16) nn16[(size_t)(i0+r)*16 + lane2] = (unsigned short)(kk & 8191ULL);
  }
}

// =====================================================================
// K3: k_suf — fused sort + Kruskal-as-MSF union-find + loss. One block.
//
// Theory: with THRESHOLD=1.0 every emitted pair merges immediately, so
// find(u) at step p == find_live(P(u)) where P = static u_max-forest root
// (all points on u's umax-chain were processed before p). The union
// sequence over peaks == Kruskal in descending weight on the edge multiset
// { (P(u_k), P(u_max(p)), w=p) : point p, distinct mapped peaks }, whose
// union edges are exactly the maximum-spanning-forest edges (within-event
// ties share the survivor side -> tie order provably irrelevant). MSF via
// parallel Boruvka; deaths via sequential replay of only the ~#peaks MSF
// edges (dying side a: death[find(a)]=p, merge into find(b)).
// =====================================================================
__global__ __launch_bounds__(1024) void k_suf(const float* __restrict__ res,
                                              const unsigned short* __restrict__ nn16,
                                              unsigned short* __restrict__ ups_t,
                                              unsigned long long* __restrict__ edges,
                                              int edgecap,
                                              float* __restrict__ out){
  __shared__ __align__(16) unsigned long long keys[NN]; // 64KB; repurposed below
  __shared__ __align__(16) unsigned short comp[NN];     // 16KB (rank inverse, then UF)
  __shared__ __align__(16) unsigned short death[NN];    // 16KB
  __shared__ __align__(16) unsigned bestv[NN];          // 32KB; -> msf u64[4096]
  __shared__ unsigned msfflag[2048];                    // 8KB (bitmask over edges)
  __shared__ float red[1024];                           // 4KB
  __shared__ unsigned long long sel[10];
  __shared__ unsigned ecnt_s, mcnt_s, chg_s, flat_s;

  float*          dens = (float*)keys;                             // [0,32KB)
  unsigned short* P    = (unsigned short*)keys + 16384;            // [32KB,48KB)
  unsigned short* hook = (unsigned short*)keys + 24576;            // [48KB,64KB)
  unsigned long long* kred = (unsigned long long*)((char*)keys + 49152); // aliases hook (time-disjoint)

  const int tid = threadIdx.x;

  // ---- A0: max(res) ----
  float m = 0.f;
  for (int t = tid; t < NN; t += 1024) m = fmaxf(m, res[t]);
  red[tid] = m; __syncthreads();
  for (int o = 512; o; o >>= 1){ if (tid < o) red[tid] = fmaxf(red[tid], red[tid+o]); __syncthreads(); }
  const float mr = red[0];

  // ---- A1: stable bitonic argsort (bit-exact vs prior rounds) ----
  for (int t = tid; t < NN; t += 1024){
    const float dnv = res[t] / mr;
    keys[t] = (((unsigned long long)__float_as_uint(dnv)) << 13) | (unsigned)t;
  }
  __syncthreads();
  for (int k = 2; k <= NN; k <<= 1){
    for (int j = k >> 1; j > 0; j >>= 1){
      for (int m2 = tid; m2 < NN/2; m2 += 1024){
        const int i = ((m2 & ~(j-1)) << 1) | (m2 & (j-1));
        const int p = i | j;
        const bool up = ((i & k) == 0);
        unsigned long long a = keys[i], b = keys[p];
        if ((a > b) == up){ keys[i] = b; keys[p] = a; }
      }
      __syncthreads();
    }
  }
  // ---- A2: rank inverse (comp used as scratch) ----
  for (int t = tid; t < NN; t += 1024)
    comp[(unsigned)(keys[t] & 8191ULL)] = (unsigned short)t;
  __syncthreads();

  // ---- A3: ups lists (desc-sorted, contiguous) + stage dens/umax in regs ----
  float dreg[8];
  unsigned short o0reg[8];
  for (int pp = 0; pp < 8; ++pp){
    const int p = tid + pp*1024;
    const unsigned long long kk = keys[p];
    dreg[pp] = __uint_as_float((unsigned)(kk >> 13));
    const unsigned orig = (unsigned)(kk & 8191ULL);
    unsigned short outv[16];
    int cnt = 0;
    for (int k = 0; k < 16; ++k){
      const unsigned r = comp[nn16[(size_t)orig*16 + k]];
      if ((int)r > p){
        int q = cnt++;
        while (q > 0 && outv[q-1] < (unsigned short)r){ outv[q] = outv[q-1]; --q; }
        outv[q] = (unsigned short)r;
      }
    }
    for (int k = cnt; k < 16; ++k) outv[k] = 0;
    o0reg[pp] = outv[0];
    unsigned short* dst = ups_t + (size_t)p*16;
    uint4 a, b;
    a.x = (unsigned)outv[0] | ((unsigned)outv[1] << 16);
    a.y = (unsigned)outv[2] | ((unsigned)outv[3] << 16);
    a.z = (unsigned)outv[4] | ((unsigned)outv[5] << 16);
    a.w = (unsigned)outv[6] | ((unsigned)outv[7] << 16);
    b.x = (unsigned)outv[8] | ((unsigned)outv[9] << 16);
    b.y = (unsigned)outv[10] | ((unsigned)outv[11] << 16);
    b.z = (unsigned)outv[12] | ((unsigned)outv[13] << 16);
    b.w = (unsigned)outv[14] | ((unsigned)outv[15] << 16);
    ((uint4*)dst)[0] = a;
    ((uint4*)dst)[1] = b;
  }
  __syncthreads();   // keys/comp reads done; safe to repurpose

  // ---- A4: dens/P/death/comp/msfflag init ----
  for (int pp = 0; pp < 8; ++pp){
    const int p = tid + pp*1024;
    dens[p] = dreg[pp];
    P[p] = (o0reg[pp] == 0) ? (unsigned short)p : o0reg[pp];
    comp[p] = (unsigned short)p;
    death[p] = 0xFFFFu;
  }
  for (int t = tid; t < 2048; t += 1024) msfflag[t] = 0u;
  if (tid == 0){ ecnt_s = 0u; mcnt_s = 0u; }
  __syncthreads();

  // ---- A5: pointer jumping -> P = u_max forest root (races benign) ----
  for (int rd = 0; rd < 13; ++rd){
    for (int pp = 0; pp < 8; ++pp){
      const int p = tid + pp*1024;
      const unsigned v = P[p];
      const unsigned w2 = P[v];
      if (w2 != v) P[p] = (unsigned short)w2;
    }
    __syncthreads();
  }

  // ---- B1: build peak-graph edge list (dedupe mapped peaks per point) ----
  for (int pp = 0; pp < 8; ++pp){
    const int p = tid + pp*1024;
    const uint4 a4 = ((const uint4*)ups_t)[(size_t)p*2];
    const uint4 b4 = ((const uint4*)ups_t)[(size_t)p*2 + 1];
    unsigned uu[8] = {a4.x, a4.y, a4.z, a4.w, b4.x, b4.y, b4.z, b4.w};
    const unsigned u0 = uu[0] & 0xFFFFu;
    if (u0 == 0u) continue;
    const unsigned m0 = P[u0];
    unsigned seen[15]; int nd = 0;
    for (int k = 1; k < 16; ++k){
      const unsigned uk = (uu[k >> 1] >> ((k & 1) * 16)) & 0xFFFFu;
      if (uk == 0u) break;                       // desc-sorted, zero-padded
      const unsigned v = P[uk];
      if (v == m0) continue;
      bool dup = false;
      for (int j = 0; j < nd; ++j) dup = dup || (seen[j] == v);
      if (dup) continue;
      seen[nd++] = v;
      const unsigned pos = atomicAdd(&ecnt_s, 1u);
      if ((int)pos < edgecap)
        edges[pos] = (((unsigned long long)(unsigned)p) << 32) | (v << 16) | m0;
    }
  }
  __syncthreads();
  const int E = ((int)ecnt_s < edgecap) ? (int)ecnt_s : edgecap;

  // ---- B2: Boruvka max-spanning-forest (keys distinct: (p+1)<<18 | eidx) ----
  for (int round = 0; round < 16; ++round){
    for (int t = tid; t < NN; t += 1024){ bestv[t] = 0u; hook[t] = 0xFFFFu; }
    if (tid == 0) chg_s = 0u;
    __syncthreads();
    for (int e = tid; e < E; e += 1024){
      const unsigned long long ed = edges[e];
      const unsigned a = (unsigned)(ed >> 16) & 0xFFFFu;
      const unsigned b = (unsigned)ed & 0xFFFFu;
      const unsigned ra = comp[a], rb = comp[b];
      if (ra != rb){
        const unsigned key = (((unsigned)(ed >> 32) + 1u) << 18) | (unsigned)e;
        atomicMax(&bestv[ra], key);
        atomicMax(&bestv[rb], key);
      }
    }
    __syncthreads();
    // choose phase (no comp writes): record hook target + mark MSF edge
    for (int t = tid; t < NN; t += 1024){
      if (comp[t] == (unsigned short)t){
        const unsigned bv = bestv[t];
        if (bv != 0u){
          const unsigned e = bv & 0x3FFFFu;
          const unsigned long long ed = edges[e];
          const unsigned a = (unsigned)(ed >> 16) & 0xFFFFu;
          const unsigned b = (unsigned)ed & 0xFFFFu;
          const unsigned ra = comp[a], rb = comp[b];
          const unsigned other = (ra == (unsigned)t) ? rb : ra;
          hook[t] = (unsigned short)other;
          atomicOr(&msfflag[e >> 5], 1u << (e & 31));
        }
      }
    }
    __syncthreads();
    // apply hooks (mutual pair: only larger id hooks)
    for (int t = tid; t < NN; t += 1024){
      const unsigned o = hook[t];
      if (o != 0xFFFFu){
        if (!(hook[o] == (unsigned short)t && (unsigned)t < o)){
          comp[t] = (unsigned short)o;
          chg_s = 1u;
        }
      }
    }
    __syncthreads();
    // flatten comp
    for (;;){
      if (tid == 0) flat_s = 0u;
      __syncthreads();
      for (int t = tid; t < NN; t += 1024){
        const unsigned c = comp[t];
        const unsigned cc = comp[c];
        if (cc != c){ comp[t] = (unsigned short)cc; flat_s = 1u; }
      }
      __syncthreads();
      if (flat_s == 0u) break;
    }
    if (chg_s == 0u) break;
  }

  // ---- B3: compact MSF edges -> u64 list (aliases bestv), sort DESC ----
  unsigned long long* msf = (unsigned long long*)bestv;   // 4096 entries
  for (int e = tid; e < E; e += 1024){
    if (msfflag[e >> 5] & (1u << (e & 31))){
      const unsigned pos = atomicAdd(&mcnt_s, 1u);
      if (pos < 4096u){
        const unsigned long long ed = edges[e];
        msf[pos] = (((ed >> 32) + 1ULL) << 32) | (ed & 0xFFFFFFFFULL);
      }
    }
  }
  __syncthreads();
  const int M = ((int)mcnt_s < 4096) ? (int)mcnt_s : 4096;
  for (int t = M + tid; t < 4096; t += 1024) msf[t] = 0ULL;
  for (int t = tid; t < NN; t += 1024) comp[t] = (unsigned short)t;  // reset for replay
  __syncthreads();
  for (int k = 2; k <= 4096; k <<= 1){
    for (int j = k >> 1; j > 0; j >>= 1){
      for (int m2 = tid; m2 < 2048; m2 += 1024){
        const int i = ((m2 & ~(j-1)) << 1) | (m2 & (j-1));
        const int p = i | j;
        const bool up = ((i & k) == 0);
        const unsigned long long a = msf[i], b = msf[p];
        if ((a < b) == up){ msf[i] = b; msf[p] = a; }   // descending
      }
      __syncthreads();
    }
  }

  // ---- B4: sequential replay of MSF edges (~#peaks, tiny) ----
  if (tid == 0){
    for (int i = 0; i < M; ++i){
      const unsigned long long e = msf[i];
      const unsigned a = ((unsigned)e >> 16) & 0xFFFFu;
      const unsigned b = (unsigned)e & 0xFFFFu;
      unsigned ra = a;
      for (;;){ const unsigned c = comp[ra]; if (c == ra) break;
                const unsigned cc = comp[c]; comp[ra] = (unsigned short)cc; ra = cc; }
      unsigned rb = b;
      for (;;){ const unsigned c = comp[rb]; if (c == rb) break;
                const unsigned cc = comp[c]; comp[rb] = (unsigned short)cc; rb = cc; }
      if (ra != rb){
        death[ra] = (unsigned short)((unsigned)(e >> 32) - 1u);
        comp[ra] = (unsigned short)rb;
      }
    }
  }
  __syncthreads();

  // ---- A8: loss (round-2 k_loss structure, bit-exact) ----
  float s = 0.f;
  for (int e = tid; e < NN; e += 1024){
    const int dr = death[e];
    if (dr != 0xFFFF) s += dens[e] - dens[dr];
  }
  red[tid] = s; __syncthreads();
  for (int o = 512; o; o >>= 1){ if (tid < o) red[tid] += red[tid+o]; __syncthreads(); }
  const float S = red[0];
  unsigned long long last = ~0ULL;
  for (int t10 = 0; t10 < 10; ++t10){
    unsigned long long km = 0ULL;
    for (int e = tid; e < NN; e += 1024){
      const int dr = death[e];
      if (dr != 0xFFFF){
        const float pers = dens[e] - dens[dr];
        const unsigned long long k = (((unsigned long long)__float_as_uint(pers)) << 13) | (unsigned)e;
        if (k < last && k > km) km = k;
      }
    }
    kred[tid] = km; __syncthreads();
    for (int o = 512; o; o >>= 1){ if (tid < o) kred[tid] = (kred[tid] > kred[tid+o]) ? kred[tid] : kred[tid+o]; __syncthreads(); }
    const unsigned long long st = kred[0];
    if (tid == 0) sel[t10] = st;
    last = st;
    __syncthreads();
  }
  if (tid == 0){
    float top = 0.f;
    for (int t10 = 0; t10 < 10; ++t10)
      if (sel[t10]) top += __uint_as_float((unsigned)(sel[t10] >> 13));
    float strong = 0.f, dest0 = 0.f, dest1 = 0.f;
    if (sel[0]){
      const unsigned e0 = (unsigned)(sel[0] & 8191ULL);
      dest0 = dens[e0]; dest1 = dens[death[e0]];
    }
    for (int t10 = 1; t10 < 10; ++t10){
      if (!sel[t10]) continue;
      const unsigned e = (unsigned)(sel[t10] & 8191ULL);
      const float a = dens[e] - dest0;
      const float b = dens[death[e]] - dest1;
      strong += sqrtf(a*a + b*b);
    }
    out[0] = (S - top) / 1.41421356237309515f + strong;
  }
}

// =====================================================================
// launch — 3 dispatches
// =====================================================================
extern "C" void kernel_launch(void* const* d_in, const int* in_sizes, int n_in,
                              void* d_out, int out_size, void* d_ws, size_t ws_size,
                              hipStream_t stream){
  const float* x = (const float*)d_in[0];
  char* w = (char*)d_ws;
  float*          sq     = (float*)(w + 0);                 // 32KB
  float*          res    = (float*)(w + 32768);             // 32KB
  unsigned short* nn16   = (unsigned short*)(w + 65536);    // 256KB
  unsigned short* ups_t  = (unsigned short*)(w + 327680);   // 256KB
  float*          xT     = (float*)(w + 589824);            // 2MB (optional)
  const int use_xt = (ws_size >= (size_t)(589824 + NN*DD*4)) ? 1 : 0;
  // edge buffer: xT region (dead after k_cand) if present, else nn16 region
  // (dead after k_suf's A3). caps keep eidx < 2^18 for the Boruvka key.
  unsigned long long* edges = use_xt ? (unsigned long long*)(w + 589824)
                                     : (unsigned long long*)(w + 65536);
  const int edgecap = use_xt ? 262143 : 32768;

  k_pre<<<128, 256, 0, stream>>>(x, xT, sq, use_xt);
  if (use_xt) k_cand<true ><<<1024, 256, 0, stream>>>(x, xT, sq, res, nn16);
  else        k_cand<false><<<1024, 256, 0, stream>>>(x, xT, sq, res, nn16);
  k_suf<<<1, 1024, 0, stream>>>(res, nn16, ups_t, edges, edgecap, (float*)d_out);
}